// Round 1
// 3717.276 us; speedup vs baseline: 1.8712x; 1.8712x over previous
//
#include <hip/hip_runtime.h>
#include <math.h>

// Model dims (fixed by the reference)
#define DMODEL 768
#define SEQL   512
#define NBATCH 8
#define NHEAD  12
#define NLAYER 6
#define FFDIM  3072
#define DHEAD  64
#define ROWS   (NBATCH * SEQL)        // 4096
#define ATTN_PER_LAYER ((size_t)NBATCH * NHEAD * SEQL * SEQL)  // 25,165,824

using f32x4 = __attribute__((ext_vector_type(4))) float;
using f16x8 = __attribute__((ext_vector_type(8))) _Float16;
using f16x4 = __attribute__((ext_vector_type(4))) _Float16;

// async global->LDS, 16B per lane; LDS dest must be wave-uniform base (HW adds lane*16)
__device__ __forceinline__ void gload16(const void* g, void* l) {
    __builtin_amdgcn_global_load_lds(
        (const __attribute__((address_space(1))) unsigned int*)g,
        (__attribute__((address_space(3))) unsigned int*)l, 16, 0, 0);
}

// ---------------------------------------------------------------------------
// Embedding + (faithful buggy) positional encoding: h[b,l,:] = emb[x[b,l],:] + pe[b,:]
__global__ __launch_bounds__(256) void embed_kernel(const int* __restrict__ x,
                                                    const float* __restrict__ emb,
                                                    float* __restrict__ h) {
    int bl = blockIdx.x;            // 0..4095 = b*512 + l
    int b = bl >> 9;
    int tok = x[bl];
    const float* e = emb + (size_t)tok * DMODEL;
    float* hp = h + (size_t)bl * DMODEL;
    const float c = -0.011992632f;  // -log(10000)/768
#pragma unroll
    for (int u = 0; u < 3; ++u) {
        int d = threadIdx.x + u * 256;
        int i = d >> 1;
        float div = expf((float)(2 * i) * c);
        float ang = (float)b * div;
        float pe = (d & 1) ? cosf(ang) : sinf(ang);
        hp[d] = e[d] + pe;
    }
}

// ---------------------------------------------------------------------------
// LayerNorm: one block per row of 768. Emits f16 hi/lo split (for MFMA GEMMs).
__global__ __launch_bounds__(256) void ln_kernel(const float* __restrict__ X,
                                                 const float* __restrict__ g,
                                                 const float* __restrict__ be,
                                                 _Float16* __restrict__ Yh,
                                                 _Float16* __restrict__ Yl) {
    int row = blockIdx.x;
    const float* x = X + (size_t)row * DMODEL;
    size_t base = (size_t)row * DMODEL;
    int t = threadIdx.x;
    float v0 = x[t], v1 = x[t + 256], v2 = x[t + 512];
    float s = v0 + v1 + v2;
    __shared__ float sb[8];
    for (int off = 32; off; off >>= 1) s += __shfl_down(s, off, 64);
    int lane = t & 63, wid = t >> 6;
    if (!lane) sb[wid] = s;
    __syncthreads();
    float mean = (sb[0] + sb[1] + sb[2] + sb[3]) * (1.0f / DMODEL);
    float d0 = v0 - mean, d1 = v1 - mean, d2 = v2 - mean;
    float q = d0 * d0 + d1 * d1 + d2 * d2;
    for (int off = 32; off; off >>= 1) q += __shfl_down(q, off, 64);
    if (!lane) sb[4 + wid] = q;
    __syncthreads();
    float var = (sb[4] + sb[5] + sb[6] + sb[7]) * (1.0f / DMODEL);
    float inv = 1.0f / sqrtf(var + 1e-5f);
    float y0 = d0 * inv * g[t] + be[t];
    float y1 = d1 * inv * g[t + 256] + be[t + 256];
    float y2 = d2 * inv * g[t + 512] + be[t + 512];
    _Float16 h0 = (_Float16)y0, h1 = (_Float16)y1, h2 = (_Float16)y2;
    Yh[base + t] = h0;       Yl[base + t] = (_Float16)(y0 - (float)h0);
    Yh[base + t + 256] = h1; Yl[base + t + 256] = (_Float16)(y1 - (float)h1);
    Yh[base + t + 512] = h2; Yl[base + t + 512] = (_Float16)(y2 - (float)h2);
}

// ---------------------------------------------------------------------------
// Weight convert+transpose: W [K][N] fp32 -> Th/Tl [N][K] f16 hi/lo.
__global__ __launch_bounds__(256) void wconv_kernel(const float* __restrict__ W,
                                                    _Float16* __restrict__ Th,
                                                    _Float16* __restrict__ Tl,
                                                    int K, int N) {
    __shared__ float t[32][33];
    int n0 = blockIdx.x * 32, k0 = blockIdx.y * 32;
    int tx = threadIdx.x & 31, ty = threadIdx.x >> 5;   // ty 0..7
#pragma unroll
    for (int u = 0; u < 4; ++u)
        t[ty + u * 8][tx] = W[(size_t)(k0 + ty + u * 8) * N + n0 + tx];
    __syncthreads();
#pragma unroll
    for (int u = 0; u < 4; ++u) {
        int r = ty + u * 8;                              // n-local
        float v = t[tx][r];                              // = W[k0+tx][n0+r]
        _Float16 hi = (_Float16)v;
        size_t o = (size_t)(n0 + r) * K + k0 + tx;
        Th[o] = hi;
        Tl[o] = (_Float16)(v - (float)hi);
    }
}

// Elementwise fp32 -> f16 hi/lo split (vectorized x4)
__global__ __launch_bounds__(256) void fconv_kernel(const float* __restrict__ X,
                                                    _Float16* __restrict__ Xh,
                                                    _Float16* __restrict__ Xl,
                                                    int n4) {
    int i = blockIdx.x * 256 + threadIdx.x;
    if (i >= n4) return;
    float4 v = ((const float4*)X)[i];
    f16x4 hh, ll;
    hh[0] = (_Float16)v.x; ll[0] = (_Float16)(v.x - (float)hh[0]);
    hh[1] = (_Float16)v.y; ll[1] = (_Float16)(v.y - (float)hh[1]);
    hh[2] = (_Float16)v.z; ll[2] = (_Float16)(v.z - (float)hh[2]);
    hh[3] = (_Float16)v.w; ll[3] = (_Float16)(v.w - (float)hh[3]);
    ((f16x4*)Xh)[i] = hh;
    ((f16x4*)Xl)[i] = ll;
}

// Concat three bias vectors of length DMODEL into one [3*DMODEL]
__global__ __launch_bounds__(256) void bcat_kernel(const float* __restrict__ a,
                                                   const float* __restrict__ b,
                                                   const float* __restrict__ c,
                                                   float* __restrict__ o) {
    int t = blockIdx.x * 256 + threadIdx.x;   // 0..2303
    o[t] = (t < DMODEL) ? a[t] : (t < 2 * DMODEL ? b[t - DMODEL] : c[t - 2 * DMODEL]);
}

// ---------------------------------------------------------------------------
// MFMA GEMM, fp32 emulated via f16 3-term split (hi*hi + hi*lo + lo*hi).
// A: [M][K] f16 hi/lo (row-major). B: [N][K] f16 hi/lo (pre-transposed weights).
// C: [M][N]. Tile 128x128, BK=32, 4 waves (each 64x64 = 4x4 frags of 16x16).
// flags: 1 = exact GELU, 2 = atomic accumulate into fp32 C (K-split via gridDim.z,
// bias applied only by z==0), 4 = write f16 hi/lo outputs Ch/Cl instead of C.
__global__ __launch_bounds__(256) void mgemm_kernel(
    const _Float16* __restrict__ Ah, const _Float16* __restrict__ Al,
    const _Float16* __restrict__ Bh, const _Float16* __restrict__ Bl,
    const float* __restrict__ bias, float* __restrict__ C,
    _Float16* __restrict__ Ch, _Float16* __restrict__ Cl,
    int N, int K, int flags) {
    __shared__ __attribute__((aligned(16))) _Float16 Ash[128][32];
    __shared__ __attribute__((aligned(16))) _Float16 Asl[128][32];
    __shared__ __attribute__((aligned(16))) _Float16 Bsh[128][32];
    __shared__ __attribute__((aligned(16))) _Float16 Bsl[128][32];

    int tid = threadIdx.x;
    int w = tid >> 6, lane = tid & 63;
    int m0 = blockIdx.y * 128, n0 = blockIdx.x * 128;
    int kper = K / gridDim.z;
    int kbeg = blockIdx.z * kper;

    // Staging: lane l covers row (ch*16 + l/4), 16B chunk (l&3). Chunk-XOR swizzle:
    // LDS slot c of row r holds global k-chunk c ^ ((r>>1)&3) -> 2-way (free) ds_read banks.
    int srow = lane >> 2;
    int kch = (lane & 3) ^ ((lane >> 3) & 3);
    size_t aoff0 = (size_t)(m0 + w * 16 + srow) * K + kch * 8;
    size_t aoff1 = (size_t)(m0 + (w + 4) * 16 + srow) * K + kch * 8;
    size_t boff0 = (size_t)(n0 + w * 16 + srow) * K + kch * 8;
    size_t boff1 = (size_t)(n0 + (w + 4) * 16 + srow) * K + kch * 8;
    _Float16* lAh0 = &Ash[w * 16][0];
    _Float16* lAh1 = &Ash[(w + 4) * 16][0];
    _Float16* lAl0 = &Asl[w * 16][0];
    _Float16* lAl1 = &Asl[(w + 4) * 16][0];
    _Float16* lBh0 = &Bsh[w * 16][0];
    _Float16* lBh1 = &Bsh[(w + 4) * 16][0];
    _Float16* lBl0 = &Bsl[w * 16][0];
    _Float16* lBl1 = &Bsl[(w + 4) * 16][0];

    // Fragment addressing: A-frag lane: row = lane&15, k = (lane>>4)*8 + i
    int fr = lane & 15, kg = lane >> 4;
    int kb = (kg ^ ((fr >> 1) & 3)) * 8;   // swizzled element offset within LDS row
    int wr = w >> 1, wc = w & 1;

    f32x4 acc[4][4];
#pragma unroll
    for (int i = 0; i < 4; ++i)
#pragma unroll
        for (int j = 0; j < 4; ++j)
#pragma unroll
            for (int r = 0; r < 4; ++r) acc[i][j][r] = 0.0f;

    for (int k0 = kbeg; k0 < kbeg + kper; k0 += 32) {
        gload16(Ah + aoff0 + k0, lAh0);
        gload16(Ah + aoff1 + k0, lAh1);
        gload16(Al + aoff0 + k0, lAl0);
        gload16(Al + aoff1 + k0, lAl1);
        gload16(Bh + boff0 + k0, lBh0);
        gload16(Bh + boff1 + k0, lBh1);
        gload16(Bl + boff0 + k0, lBl0);
        gload16(Bl + boff1 + k0, lBl1);
        asm volatile("s_waitcnt vmcnt(0)" ::: "memory");
        __syncthreads();

        f16x8 a_h[4], a_l[4], b_h[4], b_l[4];
#pragma unroll
        for (int i = 0; i < 4; ++i) {
            int r = wr * 64 + i * 16 + fr;
            a_h[i] = *(const f16x8*)&Ash[r][kb];
            a_l[i] = *(const f16x8*)&Asl[r][kb];
        }
#pragma unroll
        for (int j = 0; j < 4; ++j) {
            int r = wc * 64 + j * 16 + fr;
            b_h[j] = *(const f16x8*)&Bsh[r][kb];
            b_l[j] = *(const f16x8*)&Bsl[r][kb];
        }
#pragma unroll
        for (int i = 0; i < 4; ++i)
#pragma unroll
            for (int j = 0; j < 4; ++j) {
                acc[i][j] = __builtin_amdgcn_mfma_f32_16x16x32_f16(a_h[i], b_h[j], acc[i][j], 0, 0, 0);
                acc[i][j] = __builtin_amdgcn_mfma_f32_16x16x32_f16(a_h[i], b_l[j], acc[i][j], 0, 0, 0);
                acc[i][j] = __builtin_amdgcn_mfma_f32_16x16x32_f16(a_l[i], b_h[j], acc[i][j], 0, 0, 0);
            }
        __syncthreads();
    }

    // Epilogue. C/D frag: col = lane&15, row = (lane>>4)*4 + reg (m89-verified).
    int od = kg * 4;
#pragma unroll
    for (int j = 0; j < 4; ++j) {
        int col = n0 + wc * 64 + j * 16 + fr;
        float bv = (bias && blockIdx.z == 0) ? bias[col] : 0.0f;
#pragma unroll
        for (int i = 0; i < 4; ++i) {
#pragma unroll
            for (int r = 0; r < 4; ++r) {
                int rowg = m0 + wr * 64 + i * 16 + od + r;
                float v = acc[i][j][r] + bv;
                if (flags & 1) v = 0.5f * v * (1.0f + erff(v * 0.70710678118654752f));
                size_t o = (size_t)rowg * N + col;
                if (flags & 4) {
                    _Float16 hv = (_Float16)v;
                    Ch[o] = hv;
                    Cl[o] = (_Float16)(v - (float)hv);
                } else if (flags & 2) {
                    unsafeAtomicAdd(&C[o], v);   // HW global_atomic_add_f32
                } else {
                    C[o] = v;
                }
            }
        }
    }
}

// ---------------------------------------------------------------------------
// Generic tiled fp32 GEMM (kept for the PV step). Batched via blockIdx.z.
__global__ __launch_bounds__(256) void gemm_kernel(
    const float* __restrict__ A, const float* __restrict__ W,
    const float* __restrict__ bias, float* __restrict__ C,
    int M, int N, int K, int lda, int ldw, int ldc,
    int zmod, long long sAb, long long sAh, long long sWb, long long sWh,
    long long sCb, long long sCh, int flags) {
    int z = blockIdx.z;
    int zb = z / zmod, zh = z % zmod;
    A += zb * sAb + zh * sAh;
    W += zb * sWb + zh * sWh;
    C += zb * sCb + zh * sCh;

    __shared__ float As[16][65];
    __shared__ float Bs[16][64];
    int m0 = blockIdx.y * 64, n0 = blockIdx.x * 64;
    int tid = threadIdx.x;
    int tx = tid & 15, ty = tid >> 4;
    int arow = tid >> 2;            // 0..63
    int akk  = (tid & 3) << 2;      // 0,4,8,12
    int bkk  = tid >> 4;            // 0..15
    int bnn  = (tid & 15) << 2;     // 0..60
    float acc[4][4] = {};

    for (int k0 = 0; k0 < K; k0 += 16) {
        float4 av = *(const float4*)(A + (size_t)(m0 + arow) * lda + k0 + akk);
        float4 wv = *(const float4*)(W + (size_t)(k0 + bkk) * ldw + n0 + bnn);
        As[akk + 0][arow] = av.x;
        As[akk + 1][arow] = av.y;
        As[akk + 2][arow] = av.z;
        As[akk + 3][arow] = av.w;
        *(float4*)&Bs[bkk][bnn] = wv;
        __syncthreads();
#pragma unroll
        for (int k = 0; k < 16; ++k) {
            float a[4], bb[4];
#pragma unroll
            for (int i = 0; i < 4; ++i) a[i] = As[k][ty * 4 + i];
#pragma unroll
            for (int j = 0; j < 4; ++j) bb[j] = Bs[k][tx * 4 + j];
#pragma unroll
            for (int i = 0; i < 4; ++i)
#pragma unroll
                for (int j = 0; j < 4; ++j) acc[i][j] = fmaf(a[i], bb[j], acc[i][j]);
        }
        __syncthreads();
    }

#pragma unroll
    for (int i = 0; i < 4; ++i) {
        size_t rbase = (size_t)(m0 + ty * 4 + i) * ldc;
#pragma unroll
        for (int j = 0; j < 4; ++j) {
            int col = n0 + tx * 4 + j;
            float v = acc[i][j] + (bias ? bias[col] : 0.0f);
            if (flags & 1) v = 0.5f * v * (1.0f + erff(v * 0.70710678118654752f));
            if (flags & 2) C[rbase + col] += v;
            else           C[rbase + col] = v;
        }
    }
}

// ---------------------------------------------------------------------------
// Attention scores: P[b,h,q,k] = (Q[b,q,h,:]·K[b,k,h,:])/8 - 0.01*(q-k), mask.
// ldq = row stride of the fused QKV buffer.
__global__ __launch_bounds__(256) void scores_kernel(const float* __restrict__ Q,
                                                     const float* __restrict__ Kmat,
                                                     const int* __restrict__ mask,
                                                     float* __restrict__ P,
                                                     int ldq) {
    int kt = blockIdx.x, qt = blockIdx.y, bh = blockIdx.z;
    int b = bh / NHEAD, hh = bh % NHEAD;
    int q0 = qt * 64, k0 = kt * 32;
    __shared__ float Qs[64][65];
    __shared__ float Ks[32][65];
    const float* Qg = Q + ((size_t)(b * SEQL + q0)) * ldq + hh * DHEAD;
    const float* Kg = Kmat + ((size_t)(b * SEQL + k0)) * ldq + hh * DHEAD;
    {
        int r = threadIdx.x >> 2;
        int c0 = (threadIdx.x & 3) * 16;
#pragma unroll
        for (int u = 0; u < 4; ++u) {
            float4 v = *(const float4*)(Qg + (size_t)r * ldq + c0 + u * 4);
            Qs[r][c0 + u * 4 + 0] = v.x;
            Qs[r][c0 + u * 4 + 1] = v.y;
            Qs[r][c0 + u * 4 + 2] = v.z;
            Qs[r][c0 + u * 4 + 3] = v.w;
        }
    }
    {
        int r = threadIdx.x >> 3;
        int c0 = (threadIdx.x & 7) * 8;
#pragma unroll
        for (int u = 0; u < 2; ++u) {
            float4 v = *(const float4*)(Kg + (size_t)r * ldq + c0 + u * 4);
            Ks[r][c0 + u * 4 + 0] = v.x;
            Ks[r][c0 + u * 4 + 1] = v.y;
            Ks[r][c0 + u * 4 + 2] = v.z;
            Ks[r][c0 + u * 4 + 3] = v.w;
        }
    }
    __syncthreads();
    int tq = threadIdx.x >> 3;      // 0..31 -> q pair
    int tk = threadIdx.x & 7;       // 0..7  -> 4 k each
    float acc[2][4] = {};
#pragma unroll 8
    for (int d = 0; d < 64; ++d) {
        float qa0 = Qs[tq * 2 + 0][d];
        float qa1 = Qs[tq * 2 + 1][d];
#pragma unroll
        for (int j = 0; j < 4; ++j) {
            float kb2 = Ks[tk * 4 + j][d];
            acc[0][j] = fmaf(qa0, kb2, acc[0][j]);
            acc[1][j] = fmaf(qa1, kb2, acc[1][j]);
        }
    }
    size_t pbase = ((size_t)(b * NHEAD + hh)) * SEQL;
#pragma unroll
    for (int i = 0; i < 2; ++i) {
        int qg = q0 + tq * 2 + i;
#pragma unroll
        for (int j = 0; j < 4; ++j) {
            int kg2 = k0 + tk * 4 + j;
            float v = acc[i][j] * 0.125f - 0.01f * ((float)qg - (float)kg2);
            if (mask[b * SEQL + kg2] == 0) v = -INFINITY;
            P[(pbase + qg) * SEQL + kg2] = v;
        }
    }
}

// ---------------------------------------------------------------------------
// In-place softmax over rows of length 512. One wave per row, 4 rows/block.
__global__ __launch_bounds__(256) void softmax_kernel(float* __restrict__ P) {
    int row = blockIdx.x * 4 + (threadIdx.x >> 6);
    int lane = threadIdx.x & 63;
    float* p = P + (size_t)row * SEQL;
    float v[8];
#pragma unroll
    for (int j = 0; j < 8; ++j) v[j] = p[lane + 64 * j];
    float m = v[0];
#pragma unroll
    for (int j = 1; j < 8; ++j) m = fmaxf(m, v[j]);
    for (int off = 32; off; off >>= 1) m = fmaxf(m, __shfl_xor(m, off, 64));
    float s = 0.0f;
#pragma unroll
    for (int j = 0; j < 8; ++j) {
        v[j] = expf(v[j] - m);
        s += v[j];
    }
    for (int off = 32; off; off >>= 1) s += __shfl_xor(s, off, 64);
    float inv = 1.0f / s;
#pragma unroll
    for (int j = 0; j < 8; ++j) p[lane + 64 * j] = v[j] * inv;
}

// ---------------------------------------------------------------------------
// Final logits: out[b] = h[b,0,:]·Wc + bc. Grid = 8 blocks.
__global__ __launch_bounds__(256) void logits_kernel(const float* __restrict__ h,
                                                     const float* __restrict__ Wc,
                                                     const float* __restrict__ bc,
                                                     float* __restrict__ out) {
    int b = blockIdx.x;
    const float* hp = h + (size_t)b * SEQL * DMODEL;
    int t = threadIdx.x;
    float s = hp[t] * Wc[t] + hp[t + 256] * Wc[t + 256] + hp[t + 512] * Wc[t + 512];
    __shared__ float sb[4];
    for (int off = 32; off; off >>= 1) s += __shfl_down(s, off, 64);
    int lane = t & 63, wid = t >> 6;
    if (!lane) sb[wid] = s;
    __syncthreads();
    if (t == 0) out[b] = sb[0] + sb[1] + sb[2] + sb[3] + bc[0];
}

// ---------------------------------------------------------------------------
extern "C" void kernel_launch(void* const* d_in, const int* in_sizes, int n_in,
                              void* d_out, int out_size, void* d_ws, size_t ws_size,
                              hipStream_t stream) {
    (void)in_sizes; (void)n_in; (void)out_size; (void)ws_size;
    const int*   x    = (const int*)d_in[0];
    const int*   mask = (const int*)d_in[1];
    const float* emb  = (const float*)d_in[2];
    const float* Wq   = (const float*)d_in[3];
    const float* bq   = (const float*)d_in[4];
    const float* Wk   = (const float*)d_in[5];
    const float* bk   = (const float*)d_in[6];
    const float* Wv   = (const float*)d_in[7];
    const float* bv   = (const float*)d_in[8];
    const float* Wo   = (const float*)d_in[9];
    const float* bo   = (const float*)d_in[10];
    const float* W1   = (const float*)d_in[11];
    const float* b1   = (const float*)d_in[12];
    const float* W2   = (const float*)d_in[13];
    const float* b2   = (const float*)d_in[14];
    const float* g1   = (const float*)d_in[15];
    const float* be1  = (const float*)d_in[16];
    const float* g2   = (const float*)d_in[17];
    const float* be2  = (const float*)d_in[18];
    const float* Wc   = (const float*)d_in[19];
    const float* bc   = (const float*)d_in[20];

    float* out  = (float*)d_out;
    float* attn = out + NBATCH * 1;   // logits first (8 floats), then attn_all

    const size_t RD  = (size_t)ROWS * DMODEL;     // 3,145,728
    const size_t RFF = (size_t)ROWS * FFDIM;      // 12,582,912
    const size_t DD  = (size_t)DMODEL * DMODEL;   // 589,824
    const size_t DF  = (size_t)DMODEL * FFDIM;    // 2,359,296

    float* ws   = (float*)d_ws;
    float* h    = ws;                 // [4096][768]  fp32
    float* qkvb = h + RD;             // [4096][2304] fp32 fused Q|K|V
    float* att  = qkvb + 3 * RD;      // [4096][768]  fp32
    _Float16* xnh  = (_Float16*)(att + RD);
    _Float16* xnl  = xnh + RD;
    _Float16* atth = xnl + RD;
    _Float16* attl = atth + RD;
    _Float16* ffh  = attl + RD;       // [4096][3072] f16
    _Float16* ffl  = ffh + RFF;
    _Float16* wqkvh = ffl + RFF;      // [2304][768]  (Wq^T|Wk^T|Wv^T)
    _Float16* wqkvl = wqkvh + 3 * DD;
    _Float16* woh  = wqkvl + 3 * DD;  // [768][768]
    _Float16* wol  = woh + DD;
    _Float16* w1h  = wol + DD;        // [3072][768]
    _Float16* w1l  = w1h + DF;
    _Float16* w2h  = w1l + DF;        // [768][3072]
    _Float16* w2l  = w2h + DF;
    float* bqkv = (float*)(w2l + DF); // [2304] fp32

    embed_kernel<<<ROWS, 256, 0, stream>>>(x, emb, h);

    for (int l = 0; l < NLAYER; ++l) {
        const float* wq = Wq + (size_t)l * DD;
        const float* wk = Wk + (size_t)l * DD;
        const float* wv = Wv + (size_t)l * DD;
        const float* wo = Wo + (size_t)l * DD;
        const float* w1 = W1 + (size_t)l * DF;
        const float* w2 = W2 + (size_t)l * DF;
        float* P = attn + (size_t)l * ATTN_PER_LAYER;

        // weight convert + transpose (per-layer, reused buffers)
        wconv_kernel<<<dim3(24, 24), 256, 0, stream>>>(wq, wqkvh,          wqkvl,          DMODEL, DMODEL);
        wconv_kernel<<<dim3(24, 24), 256, 0, stream>>>(wk, wqkvh + DD,     wqkvl + DD,     DMODEL, DMODEL);
        wconv_kernel<<<dim3(24, 24), 256, 0, stream>>>(wv, wqkvh + 2 * DD, wqkvl + 2 * DD, DMODEL, DMODEL);
        wconv_kernel<<<dim3(24, 24), 256, 0, stream>>>(wo, woh, wol, DMODEL, DMODEL);
        wconv_kernel<<<dim3(96, 24), 256, 0, stream>>>(w1, w1h, w1l, DMODEL, FFDIM);
        wconv_kernel<<<dim3(24, 96), 256, 0, stream>>>(w2, w2h, w2l, FFDIM, DMODEL);
        bcat_kernel<<<9, 256, 0, stream>>>(bq + l * DMODEL, bk + l * DMODEL, bv + l * DMODEL, bqkv);

        ln_kernel<<<ROWS, 256, 0, stream>>>(h, g1 + l * DMODEL, be1 + l * DMODEL, xnh, xnl);

        // fused QKV: [4096][768] @ [768][2304] -> qkvb
        mgemm_kernel<<<dim3(18, 32, 1), 256, 0, stream>>>(
            xnh, xnl, wqkvh, wqkvl, bqkv, qkvb, nullptr, nullptr,
            3 * DMODEL, DMODEL, 0);

        scores_kernel<<<dim3(SEQL / 32, SEQL / 64, NBATCH * NHEAD), 256, 0, stream>>>(
            qkvb, qkvb + DMODEL, mask, P, 3 * DMODEL);
        softmax_kernel<<<(NBATCH * NHEAD * SEQL) / 4, 256, 0, stream>>>(P);

        // PV: per (b,h) [512x512] @ [512x64] -> att[b,q,h,:]  (V inside fused qkvb)
        gemm_kernel<<<dim3(1, SEQL / 64, NBATCH * NHEAD), 256, 0, stream>>>(
            P, qkvb + 2 * DMODEL, nullptr, att,
            SEQL, DHEAD, SEQL, SEQL, 3 * DMODEL, DMODEL,
            NHEAD,
            (long long)NHEAD * SEQL * SEQL, (long long)SEQL * SEQL,
            (long long)SEQL * 3 * DMODEL, (long long)DHEAD,
            (long long)SEQL * DMODEL, (long long)DHEAD, 0);

        fconv_kernel<<<(int)(RD / 4 / 256), 256, 0, stream>>>(att, atth, attl, (int)(RD / 4));

        // h += att @ Wo + bo   (K-split x2, atomic accumulate)
        mgemm_kernel<<<dim3(6, 32, 2), 256, 0, stream>>>(
            atth, attl, woh, wol, bo + l * DMODEL, h, nullptr, nullptr,
            DMODEL, DMODEL, 2);

        ln_kernel<<<ROWS, 256, 0, stream>>>(h, g2 + l * DMODEL, be2 + l * DMODEL, xnh, xnl);

        // ff = gelu(xn @ W1 + b1) -> f16 hi/lo directly
        mgemm_kernel<<<dim3(24, 32, 1), 256, 0, stream>>>(
            xnh, xnl, w1h, w1l, b1 + l * FFDIM, nullptr, ffh, ffl,
            FFDIM, DMODEL, 1 | 4);

        // h += ff @ W2 + b2    (K-split x4, atomic accumulate)
        mgemm_kernel<<<dim3(6, 32, 4), 256, 0, stream>>>(
            ffh, ffl, w2h, w2l, b2 + l * DMODEL, h, nullptr, nullptr,
            DMODEL, FFDIM, 2);
    }

    logits_kernel<<<NBATCH, 256, 0, stream>>>(h, Wc, bc, out);
}

// Round 2
// 3680.886 us; speedup vs baseline: 1.8897x; 1.0099x over previous
//
#include <hip/hip_runtime.h>
#include <math.h>

// Model dims (fixed by the reference)
#define DMODEL 768
#define SEQL   512
#define NBATCH 8
#define NHEAD  12
#define NLAYER 6
#define FFDIM  3072
#define DHEAD  64
#define ROWS   (NBATCH * SEQL)        // 4096
#define ATTN_PER_LAYER ((size_t)NBATCH * NHEAD * SEQL * SEQL)  // 25,165,824

using f32x4 = __attribute__((ext_vector_type(4))) float;
using f16x8 = __attribute__((ext_vector_type(8))) _Float16;
using f16x4 = __attribute__((ext_vector_type(4))) _Float16;

// async global->LDS, 16B per lane; LDS dest must be wave-uniform base (HW adds lane*16)
__device__ __forceinline__ void gload16(const void* g, void* l) {
    __builtin_amdgcn_global_load_lds(
        (const __attribute__((address_space(1))) unsigned int*)g,
        (__attribute__((address_space(3))) unsigned int*)l, 16, 0, 0);
}

// ---------------------------------------------------------------------------
// Embedding + (faithful buggy) positional encoding: h[b,l,:] = emb[x[b,l],:] + pe[b,:]
__global__ __launch_bounds__(256) void embed_kernel(const int* __restrict__ x,
                                                    const float* __restrict__ emb,
                                                    float* __restrict__ h) {
    int bl = blockIdx.x;            // 0..4095 = b*512 + l
    int b = bl >> 9;
    int tok = x[bl];
    const float* e = emb + (size_t)tok * DMODEL;
    float* hp = h + (size_t)bl * DMODEL;
    const float c = -0.011992632f;  // -log(10000)/768
#pragma unroll
    for (int u = 0; u < 3; ++u) {
        int d = threadIdx.x + u * 256;
        int i = d >> 1;
        float div = expf((float)(2 * i) * c);
        float ang = (float)b * div;
        float pe = (d & 1) ? cosf(ang) : sinf(ang);
        hp[d] = e[d] + pe;
    }
}

// ---------------------------------------------------------------------------
// LayerNorm: one block per row of 768. Emits f16 hi/lo split (for MFMA GEMMs).
__global__ __launch_bounds__(256) void ln_kernel(const float* __restrict__ X,
                                                 const float* __restrict__ g,
                                                 const float* __restrict__ be,
                                                 _Float16* __restrict__ Yh,
                                                 _Float16* __restrict__ Yl) {
    int row = blockIdx.x;
    const float* x = X + (size_t)row * DMODEL;
    size_t base = (size_t)row * DMODEL;
    int t = threadIdx.x;
    float v0 = x[t], v1 = x[t + 256], v2 = x[t + 512];
    float s = v0 + v1 + v2;
    __shared__ float sb[8];
    for (int off = 32; off; off >>= 1) s += __shfl_down(s, off, 64);
    int lane = t & 63, wid = t >> 6;
    if (!lane) sb[wid] = s;
    __syncthreads();
    float mean = (sb[0] + sb[1] + sb[2] + sb[3]) * (1.0f / DMODEL);
    float d0 = v0 - mean, d1 = v1 - mean, d2 = v2 - mean;
    float q = d0 * d0 + d1 * d1 + d2 * d2;
    for (int off = 32; off; off >>= 1) q += __shfl_down(q, off, 64);
    if (!lane) sb[4 + wid] = q;
    __syncthreads();
    float var = (sb[4] + sb[5] + sb[6] + sb[7]) * (1.0f / DMODEL);
    float inv = 1.0f / sqrtf(var + 1e-5f);
    float y0 = d0 * inv * g[t] + be[t];
    float y1 = d1 * inv * g[t + 256] + be[t + 256];
    float y2 = d2 * inv * g[t + 512] + be[t + 512];
    _Float16 h0 = (_Float16)y0, h1 = (_Float16)y1, h2 = (_Float16)y2;
    Yh[base + t] = h0;       Yl[base + t] = (_Float16)(y0 - (float)h0);
    Yh[base + t + 256] = h1; Yl[base + t + 256] = (_Float16)(y1 - (float)h1);
    Yh[base + t + 512] = h2; Yl[base + t + 512] = (_Float16)(y2 - (float)h2);
}

// ---------------------------------------------------------------------------
// Weight convert+transpose: W [K][N] fp32 -> Th/Tl [N][K] f16 hi/lo.
__global__ __launch_bounds__(256) void wconv_kernel(const float* __restrict__ W,
                                                    _Float16* __restrict__ Th,
                                                    _Float16* __restrict__ Tl,
                                                    int K, int N) {
    __shared__ float t[32][33];
    int n0 = blockIdx.x * 32, k0 = blockIdx.y * 32;
    int tx = threadIdx.x & 31, ty = threadIdx.x >> 5;   // ty 0..7
#pragma unroll
    for (int u = 0; u < 4; ++u)
        t[ty + u * 8][tx] = W[(size_t)(k0 + ty + u * 8) * N + n0 + tx];
    __syncthreads();
#pragma unroll
    for (int u = 0; u < 4; ++u) {
        int r = ty + u * 8;                              // n-local
        float v = t[tx][r];                              // = W[k0+tx][n0+r]
        _Float16 hi = (_Float16)v;
        size_t o = (size_t)(n0 + r) * K + k0 + tx;
        Th[o] = hi;
        Tl[o] = (_Float16)(v - (float)hi);
    }
}

// Concat three bias vectors of length DMODEL into one [3*DMODEL]
__global__ __launch_bounds__(256) void bcat_kernel(const float* __restrict__ a,
                                                   const float* __restrict__ b,
                                                   const float* __restrict__ c,
                                                   float* __restrict__ o) {
    int t = blockIdx.x * 256 + threadIdx.x;   // 0..2303
    o[t] = (t < DMODEL) ? a[t] : (t < 2 * DMODEL ? b[t - DMODEL] : c[t - 2 * DMODEL]);
}

// ---------------------------------------------------------------------------
// V transpose: qkv f16 hi/lo [4096][2304] (V at cols 1536+h*64) ->
// Vt [96*64][512] per (b,h): Vt[(bh*64+d)][k] = V[b,k,h*64+d].
__global__ __launch_bounds__(256) void vtrans_kernel(const _Float16* __restrict__ Vh,
                                                     const _Float16* __restrict__ Vl,
                                                     _Float16* __restrict__ Oh,
                                                     _Float16* __restrict__ Ol) {
    int kt = blockIdx.x, bh = blockIdx.y;
    int b = bh / NHEAD, hh = bh % NHEAD;
    int k0 = kt * 64;
    __shared__ _Float16 th[64][68];
    __shared__ _Float16 tl[64][68];
    int t = threadIdx.x;
    int r = t >> 2, c0 = (t & 3) * 16;
    size_t src = (size_t)(b * SEQL + k0 + r) * 2304 + 1536 + hh * DHEAD + c0;
#pragma unroll
    for (int u = 0; u < 4; ++u) {
        *(f16x4*)&th[r][c0 + u * 4] = *(const f16x4*)(Vh + src + u * 4);
        *(f16x4*)&tl[r][c0 + u * 4] = *(const f16x4*)(Vl + src + u * 4);
    }
    __syncthreads();
    int d = t >> 2, q4 = t & 3;
    size_t dst = ((size_t)bh * 64 + d) * SEQL + k0;
#pragma unroll
    for (int u = 0; u < 4; ++u) {
        int klo = (q4 + u * 4) * 4;
        f16x4 a, bb;
#pragma unroll
        for (int j = 0; j < 4; ++j) { a[j] = th[klo + j][d]; bb[j] = tl[klo + j][d]; }
        *(f16x4*)(Oh + dst + klo) = a;
        *(f16x4*)(Ol + dst + klo) = bb;
    }
}

// ---------------------------------------------------------------------------
// Fused MFMA scores + softmax. Block = 64 q rows (4 waves x 16 q), all 512 k.
// Q,K read as f16 hi/lo frags directly from the fused QKV buffer (L2-resident).
// acc[32] f32x4 = full 16x512 score strip per wave; softmax in-register
// (row q lives in the 16 lanes of a kg-group: shfl_xor 1/2/4/8). Writes P fp32.
__global__ __launch_bounds__(256) void attn_kernel(const _Float16* __restrict__ QKh,
                                                   const _Float16* __restrict__ QKl,
                                                   const int* __restrict__ mask,
                                                   float* __restrict__ P) {
    int qt = blockIdx.x, bh = blockIdx.y;
    int b = bh / NHEAD, hh = bh % NHEAD;
    int w = threadIdx.x >> 6, lane = threadIdx.x & 63;
    int fr = lane & 15, kg = lane >> 4;
    int q0 = qt * 64 + w * 16;

    __shared__ int msk[SEQL];
    msk[threadIdx.x] = mask[b * SEQL + threadIdx.x];
    msk[threadIdx.x + 256] = mask[b * SEQL + threadIdx.x + 256];
    __syncthreads();

    // Q A-frags: row = lane&15, k(d) = kg*8+i (two k-steps: d 0..31, 32..63)
    const _Float16* qrh = QKh + (size_t)(b * SEQL + q0 + fr) * 2304 + hh * DHEAD;
    const _Float16* qrl = QKl + (size_t)(b * SEQL + q0 + fr) * 2304 + hh * DHEAD;
    f16x8 ah0 = *(const f16x8*)(qrh + kg * 8);
    f16x8 ah1 = *(const f16x8*)(qrh + 32 + kg * 8);
    f16x8 al0 = *(const f16x8*)(qrl + kg * 8);
    f16x8 al1 = *(const f16x8*)(qrl + 32 + kg * 8);

    f32x4 acc[32];
#pragma unroll
    for (int nt = 0; nt < 32; ++nt)
#pragma unroll
        for (int r = 0; r < 4; ++r) acc[nt][r] = 0.0f;

    const _Float16* kbh = QKh + (size_t)(b * SEQL) * 2304 + DMODEL + hh * DHEAD;
    const _Float16* kbl = QKl + (size_t)(b * SEQL) * 2304 + DMODEL + hh * DHEAD;
#pragma unroll
    for (int nt = 0; nt < 32; ++nt) {
        // K B-frags: col(kcol) = lane&15 -> K row nt*16+fr, k(d) = kg*8+i
        const _Float16* krh = kbh + (size_t)(nt * 16 + fr) * 2304;
        const _Float16* krl = kbl + (size_t)(nt * 16 + fr) * 2304;
        f16x8 bh0 = *(const f16x8*)(krh + kg * 8);
        f16x8 bh1 = *(const f16x8*)(krh + 32 + kg * 8);
        f16x8 bl0 = *(const f16x8*)(krl + kg * 8);
        f16x8 bl1 = *(const f16x8*)(krl + 32 + kg * 8);
        f32x4 a = acc[nt];
        a = __builtin_amdgcn_mfma_f32_16x16x32_f16(ah0, bh0, a, 0, 0, 0);
        a = __builtin_amdgcn_mfma_f32_16x16x32_f16(ah1, bh1, a, 0, 0, 0);
        a = __builtin_amdgcn_mfma_f32_16x16x32_f16(ah0, bl0, a, 0, 0, 0);
        a = __builtin_amdgcn_mfma_f32_16x16x32_f16(ah1, bl1, a, 0, 0, 0);
        a = __builtin_amdgcn_mfma_f32_16x16x32_f16(al0, bh0, a, 0, 0, 0);
        a = __builtin_amdgcn_mfma_f32_16x16x32_f16(al1, bh1, a, 0, 0, 0);
        acc[nt] = a;
    }

    // scale + bias + mask, row-max (output frag: row q = kg*4+r, col k = nt*16+fr)
    float mx[4] = {-INFINITY, -INFINITY, -INFINITY, -INFINITY};
#pragma unroll
    for (int nt = 0; nt < 32; ++nt) {
        int k = nt * 16 + fr;
        float bk = 0.01f * (float)k;
        bool dead = (msk[k] == 0);
#pragma unroll
        for (int r = 0; r < 4; ++r) {
            float s = acc[nt][r] * 0.125f - 0.01f * (float)(q0 + kg * 4 + r) + bk;
            if (dead) s = -INFINITY;
            acc[nt][r] = s;
            mx[r] = fmaxf(mx[r], s);
        }
    }
    float sm[4];
#pragma unroll
    for (int r = 0; r < 4; ++r) {
        float m = mx[r];
        m = fmaxf(m, __shfl_xor(m, 1, 64));
        m = fmaxf(m, __shfl_xor(m, 2, 64));
        m = fmaxf(m, __shfl_xor(m, 4, 64));
        m = fmaxf(m, __shfl_xor(m, 8, 64));
        mx[r] = m;
        sm[r] = 0.0f;
    }
#pragma unroll
    for (int nt = 0; nt < 32; ++nt)
#pragma unroll
        for (int r = 0; r < 4; ++r) {
            float e = expf(acc[nt][r] - mx[r]);
            acc[nt][r] = e;
            sm[r] += e;
        }
#pragma unroll
    for (int r = 0; r < 4; ++r) {
        float s = sm[r];
        s += __shfl_xor(s, 1, 64);
        s += __shfl_xor(s, 2, 64);
        s += __shfl_xor(s, 4, 64);
        s += __shfl_xor(s, 8, 64);
        sm[r] = 1.0f / s;
    }
    float* prow = P + ((size_t)bh * SEQL + q0 + kg * 4) * SEQL + fr;
#pragma unroll
    for (int r = 0; r < 4; ++r)
#pragma unroll
        for (int nt = 0; nt < 32; ++nt)
            prow[(size_t)r * SEQL + nt * 16] = acc[nt][r] * sm[r];
}

// ---------------------------------------------------------------------------
// MFMA PV: O[b,q,h*64+d] = sum_k P[bh,q,k] V[k,d]. A = P fp32 (hi/lo split in
// registers), B = Vt f16 hi/lo (k-contiguous). Writes att as f16 hi/lo.
__global__ __launch_bounds__(256) void pv_kernel(const float* __restrict__ P,
                                                 const _Float16* __restrict__ Vth,
                                                 const _Float16* __restrict__ Vtl,
                                                 _Float16* __restrict__ Oh,
                                                 _Float16* __restrict__ Ol) {
    int qt = blockIdx.x, bh = blockIdx.y;
    int b = bh / NHEAD, hh = bh % NHEAD;
    int w = threadIdx.x >> 6, lane = threadIdx.x & 63;
    int fr = lane & 15, kg = lane >> 4;
    int q0 = qt * 64 + w * 16;

    const float* prow = P + ((size_t)bh * SEQL + q0 + fr) * SEQL + kg * 8;
    const _Float16* vbh[4];
    const _Float16* vbl[4];
#pragma unroll
    for (int nf = 0; nf < 4; ++nf) {
        size_t o = ((size_t)bh * 64 + nf * 16 + fr) * SEQL + kg * 8;
        vbh[nf] = Vth + o;
        vbl[nf] = Vtl + o;
    }
    f32x4 acc[4];
#pragma unroll
    for (int nf = 0; nf < 4; ++nf)
#pragma unroll
        for (int r = 0; r < 4; ++r) acc[nf][r] = 0.0f;

#pragma unroll
    for (int ks = 0; ks < 16; ++ks) {
        float4 p0 = *(const float4*)(prow + ks * 32);
        float4 p1 = *(const float4*)(prow + ks * 32 + 4);
        float pv[8] = {p0.x, p0.y, p0.z, p0.w, p1.x, p1.y, p1.z, p1.w};
        f16x8 ph, pl;
#pragma unroll
        for (int e = 0; e < 8; ++e) {
            _Float16 hv = (_Float16)pv[e];
            ph[e] = hv;
            pl[e] = (_Float16)(pv[e] - (float)hv);
        }
#pragma unroll
        for (int nf = 0; nf < 4; ++nf) {
            f16x8 vh = *(const f16x8*)(vbh[nf] + ks * 32);
            f16x8 vl = *(const f16x8*)(vbl[nf] + ks * 32);
            acc[nf] = __builtin_amdgcn_mfma_f32_16x16x32_f16(ph, vh, acc[nf], 0, 0, 0);
            acc[nf] = __builtin_amdgcn_mfma_f32_16x16x32_f16(ph, vl, acc[nf], 0, 0, 0);
            acc[nf] = __builtin_amdgcn_mfma_f32_16x16x32_f16(pl, vh, acc[nf], 0, 0, 0);
        }
    }
#pragma unroll
    for (int nf = 0; nf < 4; ++nf)
#pragma unroll
        for (int r = 0; r < 4; ++r) {
            size_t o = (size_t)(b * SEQL + q0 + kg * 4 + r) * DMODEL + hh * DHEAD + nf * 16 + fr;
            float v = acc[nf][r];
            _Float16 hv = (_Float16)v;
            Oh[o] = hv;
            Ol[o] = (_Float16)(v - (float)hv);
        }
}

// ---------------------------------------------------------------------------
// MFMA GEMM, fp32 emulated via f16 3-term split (hi*hi + hi*lo + lo*hi).
// A: [M][K] f16 hi/lo (row-major). B: [N][K] f16 hi/lo (pre-transposed weights).
// C: [M][N]. Tile 128x128, BK=32, 4 waves (each 64x64 = 4x4 frags of 16x16).
// flags: 1 = exact GELU, 2 = atomic accumulate into fp32 C (K-split via gridDim.z,
// bias applied only by z==0), 4 = write f16 hi/lo outputs Ch/Cl instead of C.
__global__ __launch_bounds__(256) void mgemm_kernel(
    const _Float16* __restrict__ Ah, const _Float16* __restrict__ Al,
    const _Float16* __restrict__ Bh, const _Float16* __restrict__ Bl,
    const float* __restrict__ bias, float* __restrict__ C,
    _Float16* __restrict__ Ch, _Float16* __restrict__ Cl,
    int N, int K, int flags) {
    __shared__ __attribute__((aligned(16))) _Float16 Ash[128][32];
    __shared__ __attribute__((aligned(16))) _Float16 Asl[128][32];
    __shared__ __attribute__((aligned(16))) _Float16 Bsh[128][32];
    __shared__ __attribute__((aligned(16))) _Float16 Bsl[128][32];

    int tid = threadIdx.x;
    int w = tid >> 6, lane = tid & 63;
    int m0 = blockIdx.y * 128, n0 = blockIdx.x * 128;
    int kper = K / gridDim.z;
    int kbeg = blockIdx.z * kper;

    int srow = lane >> 2;
    int kch = (lane & 3) ^ ((lane >> 3) & 3);
    size_t aoff0 = (size_t)(m0 + w * 16 + srow) * K + kch * 8;
    size_t aoff1 = (size_t)(m0 + (w + 4) * 16 + srow) * K + kch * 8;
    size_t boff0 = (size_t)(n0 + w * 16 + srow) * K + kch * 8;
    size_t boff1 = (size_t)(n0 + (w + 4) * 16 + srow) * K + kch * 8;
    _Float16* lAh0 = &Ash[w * 16][0];
    _Float16* lAh1 = &Ash[(w + 4) * 16][0];
    _Float16* lAl0 = &Asl[w * 16][0];
    _Float16* lAl1 = &Asl[(w + 4) * 16][0];
    _Float16* lBh0 = &Bsh[w * 16][0];
    _Float16* lBh1 = &Bsh[(w + 4) * 16][0];
    _Float16* lBl0 = &Bsl[w * 16][0];
    _Float16* lBl1 = &Bsl[(w + 4) * 16][0];

    int fr = lane & 15, kg = lane >> 4;
    int kb = (kg ^ ((fr >> 1) & 3)) * 8;
    int wr = w >> 1, wc = w & 1;

    f32x4 acc[4][4];
#pragma unroll
    for (int i = 0; i < 4; ++i)
#pragma unroll
        for (int j = 0; j < 4; ++j)
#pragma unroll
            for (int r = 0; r < 4; ++r) acc[i][j][r] = 0.0f;

    for (int k0 = kbeg; k0 < kbeg + kper; k0 += 32) {
        gload16(Ah + aoff0 + k0, lAh0);
        gload16(Ah + aoff1 + k0, lAh1);
        gload16(Al + aoff0 + k0, lAl0);
        gload16(Al + aoff1 + k0, lAl1);
        gload16(Bh + boff0 + k0, lBh0);
        gload16(Bh + boff1 + k0, lBh1);
        gload16(Bl + boff0 + k0, lBl0);
        gload16(Bl + boff1 + k0, lBl1);
        asm volatile("s_waitcnt vmcnt(0)" ::: "memory");
        __syncthreads();

        f16x8 a_h[4], a_l[4], b_h[4], b_l[4];
#pragma unroll
        for (int i = 0; i < 4; ++i) {
            int r = wr * 64 + i * 16 + fr;
            a_h[i] = *(const f16x8*)&Ash[r][kb];
            a_l[i] = *(const f16x8*)&Asl[r][kb];
        }
#pragma unroll
        for (int j = 0; j < 4; ++j) {
            int r = wc * 64 + j * 16 + fr;
            b_h[j] = *(const f16x8*)&Bsh[r][kb];
            b_l[j] = *(const f16x8*)&Bsl[r][kb];
        }
#pragma unroll
        for (int i = 0; i < 4; ++i)
#pragma unroll
            for (int j = 0; j < 4; ++j) {
                acc[i][j] = __builtin_amdgcn_mfma_f32_16x16x32_f16(a_h[i], b_h[j], acc[i][j], 0, 0, 0);
                acc[i][j] = __builtin_amdgcn_mfma_f32_16x16x32_f16(a_h[i], b_l[j], acc[i][j], 0, 0, 0);
                acc[i][j] = __builtin_amdgcn_mfma_f32_16x16x32_f16(a_l[i], b_h[j], acc[i][j], 0, 0, 0);
            }
        __syncthreads();
    }

    int od = kg * 4;
#pragma unroll
    for (int j = 0; j < 4; ++j) {
        int col = n0 + wc * 64 + j * 16 + fr;
        float bv = (bias && blockIdx.z == 0) ? bias[col] : 0.0f;
#pragma unroll
        for (int i = 0; i < 4; ++i) {
#pragma unroll
            for (int r = 0; r < 4; ++r) {
                int rowg = m0 + wr * 64 + i * 16 + od + r;
                float v = acc[i][j][r] + bv;
                if (flags & 1) v = 0.5f * v * (1.0f + erff(v * 0.70710678118654752f));
                size_t o = (size_t)rowg * N + col;
                if (flags & 4) {
                    _Float16 hv = (_Float16)v;
                    Ch[o] = hv;
                    Cl[o] = (_Float16)(v - (float)hv);
                } else if (flags & 2) {
                    unsafeAtomicAdd(&C[o], v);
                } else {
                    C[o] = v;
                }
            }
        }
    }
}

// ---------------------------------------------------------------------------
// Final logits: out[b] = h[b,0,:]·Wc + bc. Grid = 8 blocks.
__global__ __launch_bounds__(256) void logits_kernel(const float* __restrict__ h,
                                                     const float* __restrict__ Wc,
                                                     const float* __restrict__ bc,
                                                     float* __restrict__ out) {
    int b = blockIdx.x;
    const float* hp = h + (size_t)b * SEQL * DMODEL;
    int t = threadIdx.x;
    float s = hp[t] * Wc[t] + hp[t + 256] * Wc[t + 256] + hp[t + 512] * Wc[t + 512];
    __shared__ float sb[4];
    for (int off = 32; off; off >>= 1) s += __shfl_down(s, off, 64);
    int lane = t & 63, wid = t >> 6;
    if (!lane) sb[wid] = s;
    __syncthreads();
    if (t == 0) out[b] = sb[0] + sb[1] + sb[2] + sb[3] + bc[0];
}

// ---------------------------------------------------------------------------
extern "C" void kernel_launch(void* const* d_in, const int* in_sizes, int n_in,
                              void* d_out, int out_size, void* d_ws, size_t ws_size,
                              hipStream_t stream) {
    (void)in_sizes; (void)n_in; (void)out_size; (void)ws_size;
    const int*   x    = (const int*)d_in[0];
    const int*   mask = (const int*)d_in[1];
    const float* emb  = (const float*)d_in[2];
    const float* Wq   = (const float*)d_in[3];
    const float* bq   = (const float*)d_in[4];
    const float* Wk   = (const float*)d_in[5];
    const float* bk   = (const float*)d_in[6];
    const float* Wv   = (const float*)d_in[7];
    const float* bv   = (const float*)d_in[8];
    const float* Wo   = (const float*)d_in[9];
    const float* bo   = (const float*)d_in[10];
    const float* W1   = (const float*)d_in[11];
    const float* b1   = (const float*)d_in[12];
    const float* W2   = (const float*)d_in[13];
    const float* b2   = (const float*)d_in[14];
    const float* g1   = (const float*)d_in[15];
    const float* be1  = (const float*)d_in[16];
    const float* g2   = (const float*)d_in[17];
    const float* be2  = (const float*)d_in[18];
    const float* Wc   = (const float*)d_in[19];
    const float* bc   = (const float*)d_in[20];

    float* out  = (float*)d_out;
    float* attn = out + NBATCH * 1;   // logits first (8 floats), then attn_all

    const size_t RD  = (size_t)ROWS * DMODEL;     // 3,145,728
    const size_t RFF = (size_t)ROWS * FFDIM;      // 12,582,912
    const size_t DD  = (size_t)DMODEL * DMODEL;   // 589,824
    const size_t DF  = (size_t)DMODEL * FFDIM;    // 2,359,296

    float* ws   = (float*)d_ws;
    float* h    = ws;                     // [4096][768]  fp32
    _Float16* xnh  = (_Float16*)(h + RD);
    _Float16* xnl  = xnh + RD;
    _Float16* qkvh = xnl + RD;            // [4096][2304] f16 fused Q|K|V
    _Float16* qkvl = qkvh + 3 * RD;
    _Float16* vth  = qkvl + 3 * RD;       // [96*64][512] V transposed per (b,h)
    _Float16* vtl  = vth + RD;
    _Float16* atth = vtl + RD;            // [4096][768]
    _Float16* attl = atth + RD;
    _Float16* ffh  = attl + RD;           // [4096][3072]
    _Float16* ffl  = ffh + RFF;
    _Float16* wqkvh = ffl + RFF;          // [2304][768]  (Wq^T|Wk^T|Wv^T)
    _Float16* wqkvl = wqkvh + 3 * DD;
    _Float16* woh  = wqkvl + 3 * DD;      // [768][768]
    _Float16* wol  = woh + DD;
    _Float16* w1h  = wol + DD;            // [3072][768]
    _Float16* w1l  = w1h + DF;
    _Float16* w2h  = w1l + DF;            // [768][3072]
    _Float16* w2l  = w2h + DF;
    float* bqkv = (float*)(w2l + DF);     // [2304] fp32

    embed_kernel<<<ROWS, 256, 0, stream>>>(x, emb, h);

    for (int l = 0; l < NLAYER; ++l) {
        const float* wq = Wq + (size_t)l * DD;
        const float* wk = Wk + (size_t)l * DD;
        const float* wv = Wv + (size_t)l * DD;
        const float* wo = Wo + (size_t)l * DD;
        const float* w1 = W1 + (size_t)l * DF;
        const float* w2 = W2 + (size_t)l * DF;
        float* P = attn + (size_t)l * ATTN_PER_LAYER;

        wconv_kernel<<<dim3(24, 24), 256, 0, stream>>>(wq, wqkvh,          wqkvl,          DMODEL, DMODEL);
        wconv_kernel<<<dim3(24, 24), 256, 0, stream>>>(wk, wqkvh + DD,     wqkvl + DD,     DMODEL, DMODEL);
        wconv_kernel<<<dim3(24, 24), 256, 0, stream>>>(wv, wqkvh + 2 * DD, wqkvl + 2 * DD, DMODEL, DMODEL);
        wconv_kernel<<<dim3(24, 24), 256, 0, stream>>>(wo, woh, wol, DMODEL, DMODEL);
        wconv_kernel<<<dim3(96, 24), 256, 0, stream>>>(w1, w1h, w1l, DMODEL, FFDIM);
        wconv_kernel<<<dim3(24, 96), 256, 0, stream>>>(w2, w2h, w2l, FFDIM, DMODEL);
        bcat_kernel<<<9, 256, 0, stream>>>(bq + l * DMODEL, bk + l * DMODEL, bv + l * DMODEL, bqkv);

        ln_kernel<<<ROWS, 256, 0, stream>>>(h, g1 + l * DMODEL, be1 + l * DMODEL, xnh, xnl);

        // fused QKV: [4096][768] @ [768][2304] -> qkv f16 hi/lo (flag 4)
        mgemm_kernel<<<dim3(18, 32, 1), 256, 0, stream>>>(
            xnh, xnl, wqkvh, wqkvl, bqkv, nullptr, qkvh, qkvl,
            3 * DMODEL, DMODEL, 4);

        vtrans_kernel<<<dim3(SEQL / 64, NBATCH * NHEAD), 256, 0, stream>>>(
            qkvh, qkvl, vth, vtl);

        attn_kernel<<<dim3(SEQL / 64, NBATCH * NHEAD), 256, 0, stream>>>(
            qkvh, qkvl, mask, P);

        pv_kernel<<<dim3(SEQL / 64, NBATCH * NHEAD), 256, 0, stream>>>(
            P, vth, vtl, atth, attl);

        // h += att @ Wo + bo   (K-split x2, atomic accumulate)
        mgemm_kernel<<<dim3(6, 32, 2), 256, 0, stream>>>(
            atth, attl, woh, wol, bo + l * DMODEL, h, nullptr, nullptr,
            DMODEL, DMODEL, 2);

        ln_kernel<<<ROWS, 256, 0, stream>>>(h, g2 + l * DMODEL, be2 + l * DMODEL, xnh, xnl);

        // ff = gelu(xn @ W1 + b1) -> f16 hi/lo directly
        mgemm_kernel<<<dim3(24, 32, 1), 256, 0, stream>>>(
            xnh, xnl, w1h, w1l, b1 + l * FFDIM, nullptr, ffh, ffl,
            FFDIM, DMODEL, 1 | 4);

        // h += ff @ W2 + b2    (K-split x4, atomic accumulate)
        mgemm_kernel<<<dim3(6, 32, 4), 256, 0, stream>>>(
            ffh, ffl, w2h, w2l, b2 + l * DMODEL, h, nullptr, nullptr,
            DMODEL, FFDIM, 2);
    }

    logits_kernel<<<NBATCH, 256, 0, stream>>>(h, Wc, bc, out);
}

// Round 3
// 3599.656 us; speedup vs baseline: 1.9323x; 1.0226x over previous
//
#include <hip/hip_runtime.h>
#include <math.h>

// Model dims (fixed by the reference)
#define DMODEL 768
#define SEQL   512
#define NBATCH 8
#define NHEAD  12
#define NLAYER 6
#define FFDIM  3072
#define DHEAD  64
#define ROWS   (NBATCH * SEQL)        // 4096
#define ATTN_PER_LAYER ((size_t)NBATCH * NHEAD * SEQL * SEQL)  // 25,165,824

using f32x4 = __attribute__((ext_vector_type(4))) float;
using f16x8 = __attribute__((ext_vector_type(8))) _Float16;
using f16x4 = __attribute__((ext_vector_type(4))) _Float16;

// async global->LDS, 16B per lane; LDS dest must be wave-uniform base (HW adds lane*16)
__device__ __forceinline__ void gload16(const void* g, void* l) {
    __builtin_amdgcn_global_load_lds(
        (const __attribute__((address_space(1))) unsigned int*)g,
        (__attribute__((address_space(3))) unsigned int*)l, 16, 0, 0);
}

// ---------------------------------------------------------------------------
// Embedding + (faithful buggy) positional encoding: h[b,l,:] = emb[x[b,l],:] + pe[b,:]
__global__ __launch_bounds__(256) void embed_kernel(const int* __restrict__ x,
                                                    const float* __restrict__ emb,
                                                    float* __restrict__ h) {
    int bl = blockIdx.x;            // 0..4095 = b*512 + l
    int b = bl >> 9;
    int tok = x[bl];
    const float* e = emb + (size_t)tok * DMODEL;
    float* hp = h + (size_t)bl * DMODEL;
    const float c = -0.011992632f;  // -log(10000)/768
#pragma unroll
    for (int u = 0; u < 3; ++u) {
        int d = threadIdx.x + u * 256;
        int i = d >> 1;
        float div = expf((float)(2 * i) * c);
        float ang = (float)b * div;
        float pe = (d & 1) ? cosf(ang) : sinf(ang);
        hp[d] = e[d] + pe;
    }
}

// ---------------------------------------------------------------------------
// LayerNorm: one block per row of 768. Emits f16 hi/lo split (for MFMA GEMMs).
__global__ __launch_bounds__(256) void ln_kernel(const float* __restrict__ X,
                                                 const float* __restrict__ g,
                                                 const float* __restrict__ be,
                                                 _Float16* __restrict__ Yh,
                                                 _Float16* __restrict__ Yl) {
    int row = blockIdx.x;
    const float* x = X + (size_t)row * DMODEL;
    size_t base = (size_t)row * DMODEL;
    int t = threadIdx.x;
    float v0 = x[t], v1 = x[t + 256], v2 = x[t + 512];
    float s = v0 + v1 + v2;
    __shared__ float sb[8];
    for (int off = 32; off; off >>= 1) s += __shfl_down(s, off, 64);
    int lane = t & 63, wid = t >> 6;
    if (!lane) sb[wid] = s;
    __syncthreads();
    float mean = (sb[0] + sb[1] + sb[2] + sb[3]) * (1.0f / DMODEL);
    float d0 = v0 - mean, d1 = v1 - mean, d2 = v2 - mean;
    float q = d0 * d0 + d1 * d1 + d2 * d2;
    for (int off = 32; off; off >>= 1) q += __shfl_down(q, off, 64);
    if (!lane) sb[4 + wid] = q;
    __syncthreads();
    float var = (sb[4] + sb[5] + sb[6] + sb[7]) * (1.0f / DMODEL);
    float inv = 1.0f / sqrtf(var + 1e-5f);
    float y0 = d0 * inv * g[t] + be[t];
    float y1 = d1 * inv * g[t + 256] + be[t + 256];
    float y2 = d2 * inv * g[t + 512] + be[t + 512];
    _Float16 h0 = (_Float16)y0, h1 = (_Float16)y1, h2 = (_Float16)y2;
    Yh[base + t] = h0;       Yl[base + t] = (_Float16)(y0 - (float)h0);
    Yh[base + t + 256] = h1; Yl[base + t + 256] = (_Float16)(y1 - (float)h1);
    Yh[base + t + 512] = h2; Yl[base + t + 512] = (_Float16)(y2 - (float)h2);
}

// ---------------------------------------------------------------------------
// Weight convert+transpose: W [K][N] fp32 -> Th/Tl [N][K] f16 hi/lo.
__global__ __launch_bounds__(256) void wconv_kernel(const float* __restrict__ W,
                                                    _Float16* __restrict__ Th,
                                                    _Float16* __restrict__ Tl,
                                                    int K, int N) {
    __shared__ float t[32][33];
    int n0 = blockIdx.x * 32, k0 = blockIdx.y * 32;
    int tx = threadIdx.x & 31, ty = threadIdx.x >> 5;   // ty 0..7
#pragma unroll
    for (int u = 0; u < 4; ++u)
        t[ty + u * 8][tx] = W[(size_t)(k0 + ty + u * 8) * N + n0 + tx];
    __syncthreads();
#pragma unroll
    for (int u = 0; u < 4; ++u) {
        int r = ty + u * 8;                              // n-local
        float v = t[tx][r];                              // = W[k0+tx][n0+r]
        _Float16 hi = (_Float16)v;
        size_t o = (size_t)(n0 + r) * K + k0 + tx;
        Th[o] = hi;
        Tl[o] = (_Float16)(v - (float)hi);
    }
}

// Concat three bias vectors of length DMODEL into one [3*DMODEL]
__global__ __launch_bounds__(256) void bcat_kernel(const float* __restrict__ a,
                                                   const float* __restrict__ b,
                                                   const float* __restrict__ c,
                                                   float* __restrict__ o) {
    int t = blockIdx.x * 256 + threadIdx.x;   // 0..2303
    o[t] = (t < DMODEL) ? a[t] : (t < 2 * DMODEL ? b[t - DMODEL] : c[t - 2 * DMODEL]);
}

// ---------------------------------------------------------------------------
// V transpose: qkv f16 hi/lo [4096][2304] (V at cols 1536+h*64) ->
// Vt [96*64][512] per (b,h): Vt[(bh*64+d)][k] = V[b,k,h*64+d].
__global__ __launch_bounds__(256) void vtrans_kernel(const _Float16* __restrict__ Vh,
                                                     const _Float16* __restrict__ Vl,
                                                     _Float16* __restrict__ Oh,
                                                     _Float16* __restrict__ Ol) {
    int kt = blockIdx.x, bh = blockIdx.y;
    int b = bh / NHEAD, hh = bh % NHEAD;
    int k0 = kt * 64;
    __shared__ _Float16 th[64][68];
    __shared__ _Float16 tl[64][68];
    int t = threadIdx.x;
    int r = t >> 2, c0 = (t & 3) * 16;
    size_t src = (size_t)(b * SEQL + k0 + r) * 2304 + 1536 + hh * DHEAD + c0;
#pragma unroll
    for (int u = 0; u < 4; ++u) {
        *(f16x4*)&th[r][c0 + u * 4] = *(const f16x4*)(Vh + src + u * 4);
        *(f16x4*)&tl[r][c0 + u * 4] = *(const f16x4*)(Vl + src + u * 4);
    }
    __syncthreads();
    int d = t >> 2, q4 = t & 3;
    size_t dst = ((size_t)bh * 64 + d) * SEQL + k0;
#pragma unroll
    for (int u = 0; u < 4; ++u) {
        int klo = (q4 + u * 4) * 4;
        f16x4 a, bb;
#pragma unroll
        for (int j = 0; j < 4; ++j) { a[j] = th[klo + j][d]; bb[j] = tl[klo + j][d]; }
        *(f16x4*)(Oh + dst + klo) = a;
        *(f16x4*)(Ol + dst + klo) = bb;
    }
}

// ---------------------------------------------------------------------------
// Fused MFMA scores + softmax. Block = 64 q rows (4 waves x 16 q), all 512 k.
// Q,K read as f16 hi/lo frags directly from the fused QKV buffer (L2-resident).
// acc[32] f32x4 = full 16x512 score strip per wave; softmax in-register
// (row q lives in the 16 lanes of a kg-group: shfl_xor 1/2/4/8). Writes P fp32.
__global__ __launch_bounds__(256) void attn_kernel(const _Float16* __restrict__ QKh,
                                                   const _Float16* __restrict__ QKl,
                                                   const int* __restrict__ mask,
                                                   float* __restrict__ P) {
    int qt = blockIdx.x, bh = blockIdx.y;
    int b = bh / NHEAD, hh = bh % NHEAD;
    int w = threadIdx.x >> 6, lane = threadIdx.x & 63;
    int fr = lane & 15, kg = lane >> 4;
    int q0 = qt * 64 + w * 16;

    __shared__ int msk[SEQL];
    msk[threadIdx.x] = mask[b * SEQL + threadIdx.x];
    msk[threadIdx.x + 256] = mask[b * SEQL + threadIdx.x + 256];
    __syncthreads();

    // Q A-frags: row = lane&15, k(d) = kg*8+i (two k-steps: d 0..31, 32..63)
    const _Float16* qrh = QKh + (size_t)(b * SEQL + q0 + fr) * 2304 + hh * DHEAD;
    const _Float16* qrl = QKl + (size_t)(b * SEQL + q0 + fr) * 2304 + hh * DHEAD;
    f16x8 ah0 = *(const f16x8*)(qrh + kg * 8);
    f16x8 ah1 = *(const f16x8*)(qrh + 32 + kg * 8);
    f16x8 al0 = *(const f16x8*)(qrl + kg * 8);
    f16x8 al1 = *(const f16x8*)(qrl + 32 + kg * 8);

    f32x4 acc[32];
#pragma unroll
    for (int nt = 0; nt < 32; ++nt)
#pragma unroll
        for (int r = 0; r < 4; ++r) acc[nt][r] = 0.0f;

    const _Float16* kbh = QKh + (size_t)(b * SEQL) * 2304 + DMODEL + hh * DHEAD;
    const _Float16* kbl = QKl + (size_t)(b * SEQL) * 2304 + DMODEL + hh * DHEAD;
#pragma unroll
    for (int nt = 0; nt < 32; ++nt) {
        // K B-frags: col(kcol) = lane&15 -> K row nt*16+fr, k(d) = kg*8+i
        const _Float16* krh = kbh + (size_t)(nt * 16 + fr) * 2304;
        const _Float16* krl = kbl + (size_t)(nt * 16 + fr) * 2304;
        f16x8 bh0 = *(const f16x8*)(krh + kg * 8);
        f16x8 bh1 = *(const f16x8*)(krh + 32 + kg * 8);
        f16x8 bl0 = *(const f16x8*)(krl + kg * 8);
        f16x8 bl1 = *(const f16x8*)(krl + 32 + kg * 8);
        f32x4 a = acc[nt];
        a = __builtin_amdgcn_mfma_f32_16x16x32_f16(ah0, bh0, a, 0, 0, 0);
        a = __builtin_amdgcn_mfma_f32_16x16x32_f16(ah1, bh1, a, 0, 0, 0);
        a = __builtin_amdgcn_mfma_f32_16x16x32_f16(ah0, bl0, a, 0, 0, 0);
        a = __builtin_amdgcn_mfma_f32_16x16x32_f16(ah1, bl1, a, 0, 0, 0);
        a = __builtin_amdgcn_mfma_f32_16x16x32_f16(al0, bh0, a, 0, 0, 0);
        a = __builtin_amdgcn_mfma_f32_16x16x32_f16(al1, bh1, a, 0, 0, 0);
        acc[nt] = a;
    }

    // scale + bias + mask, row-max (output frag: row q = kg*4+r, col k = nt*16+fr)
    float mx[4] = {-INFINITY, -INFINITY, -INFINITY, -INFINITY};
#pragma unroll
    for (int nt = 0; nt < 32; ++nt) {
        int k = nt * 16 + fr;
        float bk = 0.01f * (float)k;
        bool dead = (msk[k] == 0);
#pragma unroll
        for (int r = 0; r < 4; ++r) {
            float s = acc[nt][r] * 0.125f - 0.01f * (float)(q0 + kg * 4 + r) + bk;
            if (dead) s = -INFINITY;
            acc[nt][r] = s;
            mx[r] = fmaxf(mx[r], s);
        }
    }
    float sm[4];
#pragma unroll
    for (int r = 0; r < 4; ++r) {
        float m = mx[r];
        m = fmaxf(m, __shfl_xor(m, 1, 64));
        m = fmaxf(m, __shfl_xor(m, 2, 64));
        m = fmaxf(m, __shfl_xor(m, 4, 64));
        m = fmaxf(m, __shfl_xor(m, 8, 64));
        mx[r] = m;
        sm[r] = 0.0f;
    }
#pragma unroll
    for (int nt = 0; nt < 32; ++nt)
#pragma unroll
        for (int r = 0; r < 4; ++r) {
            float e = expf(acc[nt][r] - mx[r]);
            acc[nt][r] = e;
            sm[r] += e;
        }
#pragma unroll
    for (int r = 0; r < 4; ++r) {
        float s = sm[r];
        s += __shfl_xor(s, 1, 64);
        s += __shfl_xor(s, 2, 64);
        s += __shfl_xor(s, 4, 64);
        s += __shfl_xor(s, 8, 64);
        sm[r] = 1.0f / s;
    }
    float* prow = P + ((size_t)bh * SEQL + q0 + kg * 4) * SEQL + fr;
#pragma unroll
    for (int r = 0; r < 4; ++r)
#pragma unroll
        for (int nt = 0; nt < 32; ++nt)
            prow[(size_t)r * SEQL + nt * 16] = acc[nt][r] * sm[r];
}

// ---------------------------------------------------------------------------
// MFMA PV: O[b,q,h*64+d] = sum_k P[bh,q,k] V[k,d]. A = P fp32 (hi/lo split in
// registers), B = Vt f16 hi/lo (k-contiguous). Writes att as f16 hi/lo.
__global__ __launch_bounds__(256) void pv_kernel(const float* __restrict__ P,
                                                 const _Float16* __restrict__ Vth,
                                                 const _Float16* __restrict__ Vtl,
                                                 _Float16* __restrict__ Oh,
                                                 _Float16* __restrict__ Ol) {
    int qt = blockIdx.x, bh = blockIdx.y;
    int b = bh / NHEAD, hh = bh % NHEAD;
    int w = threadIdx.x >> 6, lane = threadIdx.x & 63;
    int fr = lane & 15, kg = lane >> 4;
    int q0 = qt * 64 + w * 16;

    const float* prow = P + ((size_t)bh * SEQL + q0 + fr) * SEQL + kg * 8;
    const _Float16* vbh[4];
    const _Float16* vbl[4];
#pragma unroll
    for (int nf = 0; nf < 4; ++nf) {
        size_t o = ((size_t)bh * 64 + nf * 16 + fr) * SEQL + kg * 8;
        vbh[nf] = Vth + o;
        vbl[nf] = Vtl + o;
    }
    f32x4 acc[4];
#pragma unroll
    for (int nf = 0; nf < 4; ++nf)
#pragma unroll
        for (int r = 0; r < 4; ++r) acc[nf][r] = 0.0f;

#pragma unroll
    for (int ks = 0; ks < 16; ++ks) {
        float4 p0 = *(const float4*)(prow + ks * 32);
        float4 p1 = *(const float4*)(prow + ks * 32 + 4);
        float pv[8] = {p0.x, p0.y, p0.z, p0.w, p1.x, p1.y, p1.z, p1.w};
        f16x8 ph, pl;
#pragma unroll
        for (int e = 0; e < 8; ++e) {
            _Float16 hv = (_Float16)pv[e];
            ph[e] = hv;
            pl[e] = (_Float16)(pv[e] - (float)hv);
        }
#pragma unroll
        for (int nf = 0; nf < 4; ++nf) {
            f16x8 vh = *(const f16x8*)(vbh[nf] + ks * 32);
            f16x8 vl = *(const f16x8*)(vbl[nf] + ks * 32);
            acc[nf] = __builtin_amdgcn_mfma_f32_16x16x32_f16(ph, vh, acc[nf], 0, 0, 0);
            acc[nf] = __builtin_amdgcn_mfma_f32_16x16x32_f16(ph, vl, acc[nf], 0, 0, 0);
            acc[nf] = __builtin_amdgcn_mfma_f32_16x16x32_f16(pl, vh, acc[nf], 0, 0, 0);
        }
    }
#pragma unroll
    for (int nf = 0; nf < 4; ++nf)
#pragma unroll
        for (int r = 0; r < 4; ++r) {
            size_t o = (size_t)(b * SEQL + q0 + kg * 4 + r) * DMODEL + hh * DHEAD + nf * 16 + fr;
            float v = acc[nf][r];
            _Float16 hv = (_Float16)v;
            Oh[o] = hv;
            Ol[o] = (_Float16)(v - (float)hv);
        }
}

// ---------------------------------------------------------------------------
// MFMA GEMM, fp32 emulated via f16 3-term split (hi*hi + hi*lo + lo*hi).
// A: [M][K] f16 hi/lo (row-major). B: [N][K] f16 hi/lo (pre-transposed weights).
// C: [M][N]. Tile 128x128, BK=32, 4 waves (each 64x64 = 4x4 frags of 16x16).
// 2-phase double-buffered pipeline (T3 minimum recipe): STAGE(next) issued right
// after the barrier so the 8 global_load_lds fly under ds_read+MFMA; one raw
// s_barrier + per-wave vmcnt(0) per chunk (NOT __syncthreads, which would drain
// the prefetch).
// flags: 1 = exact GELU, 2 = atomic accumulate into fp32 C (K-split via gridDim.z,
// bias applied only by z==0), 4 = write f16 hi/lo outputs Ch/Cl instead of C.
__global__ __launch_bounds__(256) void mgemm_kernel(
    const _Float16* __restrict__ Ah, const _Float16* __restrict__ Al,
    const _Float16* __restrict__ Bh, const _Float16* __restrict__ Bl,
    const float* __restrict__ bias, float* __restrict__ C,
    _Float16* __restrict__ Ch, _Float16* __restrict__ Cl,
    int N, int K, int flags) {
    __shared__ __attribute__((aligned(16))) _Float16 Ash[2][128][32];
    __shared__ __attribute__((aligned(16))) _Float16 Asl[2][128][32];
    __shared__ __attribute__((aligned(16))) _Float16 Bsh[2][128][32];
    __shared__ __attribute__((aligned(16))) _Float16 Bsl[2][128][32];

    int tid = threadIdx.x;
    int w = tid >> 6, lane = tid & 63;
    int m0 = blockIdx.y * 128, n0 = blockIdx.x * 128;
    int kper = K / gridDim.z;
    int kbeg = blockIdx.z * kper;

    // Staging: lane l covers row (l>>2) of its 16-row group, 16B chunk (l&3),
    // with chunk-XOR swizzle pre-applied to the GLOBAL source (LDS stays linear).
    int srow = lane >> 2;
    int kch = (lane & 3) ^ ((lane >> 3) & 3);
    size_t aoff0 = (size_t)(m0 + w * 16 + srow) * K + kch * 8;
    size_t aoff1 = (size_t)(m0 + (w + 4) * 16 + srow) * K + kch * 8;
    size_t boff0 = (size_t)(n0 + w * 16 + srow) * K + kch * 8;
    size_t boff1 = (size_t)(n0 + (w + 4) * 16 + srow) * K + kch * 8;
    int r0 = w * 16, r1 = (w + 4) * 16;

    // Fragment addressing: A-frag lane: row = lane&15, k = (lane>>4)*8 + i
    int fr = lane & 15, kg = lane >> 4;
    int kb = (kg ^ ((fr >> 1) & 3)) * 8;   // swizzled element offset within LDS row
    int wr = w >> 1, wc = w & 1;

    f32x4 acc[4][4];
#pragma unroll
    for (int i = 0; i < 4; ++i)
#pragma unroll
        for (int j = 0; j < 4; ++j)
#pragma unroll
            for (int r = 0; r < 4; ++r) acc[i][j][r] = 0.0f;

    int nt = kper >> 5;
    // prologue: stage chunk 0 into buffer 0
    {
        int k0 = kbeg;
        gload16(Ah + aoff0 + k0, &Ash[0][r0][0]);
        gload16(Ah + aoff1 + k0, &Ash[0][r1][0]);
        gload16(Al + aoff0 + k0, &Asl[0][r0][0]);
        gload16(Al + aoff1 + k0, &Asl[0][r1][0]);
        gload16(Bh + boff0 + k0, &Bsh[0][r0][0]);
        gload16(Bh + boff1 + k0, &Bsh[0][r1][0]);
        gload16(Bl + boff0 + k0, &Bsl[0][r0][0]);
        gload16(Bl + boff1 + k0, &Bsl[0][r1][0]);
    }

    for (int t = 0; t < nt; ++t) {
        int cur = t & 1;
        // my 8 outstanding loads (buf[cur]) done, then all waves' loads done
        asm volatile("s_waitcnt vmcnt(0)" ::: "memory");
        __builtin_amdgcn_s_barrier();
        __builtin_amdgcn_sched_barrier(0);

        // issue next-chunk staging into buf[cur^1] (reads of buf[cur^1] finished
        // before this barrier); these loads fly under the MFMAs below
        if (t + 1 < nt) {
            int k0 = kbeg + (t + 1) * 32;
            int nb = cur ^ 1;
            gload16(Ah + aoff0 + k0, &Ash[nb][r0][0]);
            gload16(Ah + aoff1 + k0, &Ash[nb][r1][0]);
            gload16(Al + aoff0 + k0, &Asl[nb][r0][0]);
            gload16(Al + aoff1 + k0, &Asl[nb][r1][0]);
            gload16(Bh + boff0 + k0, &Bsh[nb][r0][0]);
            gload16(Bh + boff1 + k0, &Bsh[nb][r1][0]);
            gload16(Bl + boff0 + k0, &Bsl[nb][r0][0]);
            gload16(Bl + boff1 + k0, &Bsl[nb][r1][0]);
        }

        f16x8 a_h[4], a_l[4], b_h[4], b_l[4];
#pragma unroll
        for (int i = 0; i < 4; ++i) {
            int r = wr * 64 + i * 16 + fr;
            a_h[i] = *(const f16x8*)&Ash[cur][r][kb];
            a_l[i] = *(const f16x8*)&Asl[cur][r][kb];
        }
#pragma unroll
        for (int j = 0; j < 4; ++j) {
            int r = wc * 64 + j * 16 + fr;
            b_h[j] = *(const f16x8*)&Bsh[cur][r][kb];
            b_l[j] = *(const f16x8*)&Bsl[cur][r][kb];
        }
#pragma unroll
        for (int i = 0; i < 4; ++i)
#pragma unroll
            for (int j = 0; j < 4; ++j) {
                acc[i][j] = __builtin_amdgcn_mfma_f32_16x16x32_f16(a_h[i], b_h[j], acc[i][j], 0, 0, 0);
                acc[i][j] = __builtin_amdgcn_mfma_f32_16x16x32_f16(a_h[i], b_l[j], acc[i][j], 0, 0, 0);
                acc[i][j] = __builtin_amdgcn_mfma_f32_16x16x32_f16(a_l[i], b_h[j], acc[i][j], 0, 0, 0);
            }
        // no trailing barrier: next iteration's vmcnt(0)+s_barrier provides the
        // cross-wave ordering (all ds_reads of buf[cur] completed before each
        // wave's last MFMA, which precedes its next-iteration barrier)
    }

    // Epilogue. C/D frag: col = lane&15, row = (lane>>4)*4 + reg (m89-verified).
    int od = kg * 4;
#pragma unroll
    for (int j = 0; j < 4; ++j) {
        int col = n0 + wc * 64 + j * 16 + fr;
        float bv = (bias && blockIdx.z == 0) ? bias[col] : 0.0f;
#pragma unroll
        for (int i = 0; i < 4; ++i) {
#pragma unroll
            for (int r = 0; r < 4; ++r) {
                int rowg = m0 + wr * 64 + i * 16 + od + r;
                float v = acc[i][j][r] + bv;
                if (flags & 1) v = 0.5f * v * (1.0f + erff(v * 0.70710678118654752f));
                size_t o = (size_t)rowg * N + col;
                if (flags & 4) {
                    _Float16 hv = (_Float16)v;
                    Ch[o] = hv;
                    Cl[o] = (_Float16)(v - (float)hv);
                } else if (flags & 2) {
                    unsafeAtomicAdd(&C[o], v);
                } else {
                    C[o] = v;
                }
            }
        }
    }
}

// ---------------------------------------------------------------------------
// Final logits: out[b] = h[b,0,:]·Wc + bc. Grid = 8 blocks.
__global__ __launch_bounds__(256) void logits_kernel(const float* __restrict__ h,
                                                     const float* __restrict__ Wc,
                                                     const float* __restrict__ bc,
                                                     float* __restrict__ out) {
    int b = blockIdx.x;
    const float* hp = h + (size_t)b * SEQL * DMODEL;
    int t = threadIdx.x;
    float s = hp[t] * Wc[t] + hp[t + 256] * Wc[t + 256] + hp[t + 512] * Wc[t + 512];
    __shared__ float sb[4];
    for (int off = 32; off; off >>= 1) s += __shfl_down(s, off, 64);
    int lane = t & 63, wid = t >> 6;
    if (!lane) sb[wid] = s;
    __syncthreads();
    if (t == 0) out[b] = sb[0] + sb[1] + sb[2] + sb[3] + bc[0];
}

// ---------------------------------------------------------------------------
extern "C" void kernel_launch(void* const* d_in, const int* in_sizes, int n_in,
                              void* d_out, int out_size, void* d_ws, size_t ws_size,
                              hipStream_t stream) {
    (void)in_sizes; (void)n_in; (void)out_size; (void)ws_size;
    const int*   x    = (const int*)d_in[0];
    const int*   mask = (const int*)d_in[1];
    const float* emb  = (const float*)d_in[2];
    const float* Wq   = (const float*)d_in[3];
    const float* bq   = (const float*)d_in[4];
    const float* Wk   = (const float*)d_in[5];
    const float* bk   = (const float*)d_in[6];
    const float* Wv   = (const float*)d_in[7];
    const float* bv   = (const float*)d_in[8];
    const float* Wo   = (const float*)d_in[9];
    const float* bo   = (const float*)d_in[10];
    const float* W1   = (const float*)d_in[11];
    const float* b1   = (const float*)d_in[12];
    const float* W2   = (const float*)d_in[13];
    const float* b2   = (const float*)d_in[14];
    const float* g1   = (const float*)d_in[15];
    const float* be1  = (const float*)d_in[16];
    const float* g2   = (const float*)d_in[17];
    const float* be2  = (const float*)d_in[18];
    const float* Wc   = (const float*)d_in[19];
    const float* bc   = (const float*)d_in[20];

    float* out  = (float*)d_out;
    float* attn = out + NBATCH * 1;   // logits first (8 floats), then attn_all

    const size_t RD  = (size_t)ROWS * DMODEL;     // 3,145,728
    const size_t RFF = (size_t)ROWS * FFDIM;      // 12,582,912
    const size_t DD  = (size_t)DMODEL * DMODEL;   // 589,824
    const size_t DF  = (size_t)DMODEL * FFDIM;    // 2,359,296

    float* ws   = (float*)d_ws;
    float* h    = ws;                     // [4096][768]  fp32
    _Float16* xnh  = (_Float16*)(h + RD);
    _Float16* xnl  = xnh + RD;
    _Float16* qkvh = xnl + RD;            // [4096][2304] f16 fused Q|K|V
    _Float16* qkvl = qkvh + 3 * RD;
    _Float16* vth  = qkvl + 3 * RD;       // [96*64][512] V transposed per (b,h)
    _Float16* vtl  = vth + RD;
    _Float16* atth = vtl + RD;            // [4096][768]
    _Float16* attl = atth + RD;
    _Float16* ffh  = attl + RD;           // [4096][3072]
    _Float16* ffl  = ffh + RFF;
    _Float16* wqkvh = ffl + RFF;          // [2304][768]  (Wq^T|Wk^T|Wv^T)
    _Float16* wqkvl = wqkvh + 3 * DD;
    _Float16* woh  = wqkvl + 3 * DD;      // [768][768]
    _Float16* wol  = woh + DD;
    _Float16* w1h  = wol + DD;            // [3072][768]
    _Float16* w1l  = w1h + DF;
    _Float16* w2h  = w1l + DF;            // [768][3072]
    _Float16* w2l  = w2h + DF;
    float* bqkv = (float*)(w2l + DF);     // [2304] fp32

    embed_kernel<<<ROWS, 256, 0, stream>>>(x, emb, h);

    for (int l = 0; l < NLAYER; ++l) {
        const float* wq = Wq + (size_t)l * DD;
        const float* wk = Wk + (size_t)l * DD;
        const float* wv = Wv + (size_t)l * DD;
        const float* wo = Wo + (size_t)l * DD;
        const float* w1 = W1 + (size_t)l * DF;
        const float* w2 = W2 + (size_t)l * DF;
        float* P = attn + (size_t)l * ATTN_PER_LAYER;

        wconv_kernel<<<dim3(24, 24), 256, 0, stream>>>(wq, wqkvh,          wqkvl,          DMODEL, DMODEL);
        wconv_kernel<<<dim3(24, 24), 256, 0, stream>>>(wk, wqkvh + DD,     wqkvl + DD,     DMODEL, DMODEL);
        wconv_kernel<<<dim3(24, 24), 256, 0, stream>>>(wv, wqkvh + 2 * DD, wqkvl + 2 * DD, DMODEL, DMODEL);
        wconv_kernel<<<dim3(24, 24), 256, 0, stream>>>(wo, woh, wol, DMODEL, DMODEL);
        wconv_kernel<<<dim3(96, 24), 256, 0, stream>>>(w1, w1h, w1l, DMODEL, FFDIM);
        wconv_kernel<<<dim3(24, 96), 256, 0, stream>>>(w2, w2h, w2l, FFDIM, DMODEL);
        bcat_kernel<<<9, 256, 0, stream>>>(bq + l * DMODEL, bk + l * DMODEL, bv + l * DMODEL, bqkv);

        ln_kernel<<<ROWS, 256, 0, stream>>>(h, g1 + l * DMODEL, be1 + l * DMODEL, xnh, xnl);

        // fused QKV: [4096][768] @ [768][2304] -> qkv f16 hi/lo (flag 4)
        mgemm_kernel<<<dim3(18, 32, 1), 256, 0, stream>>>(
            xnh, xnl, wqkvh, wqkvl, bqkv, nullptr, qkvh, qkvl,
            3 * DMODEL, DMODEL, 4);

        vtrans_kernel<<<dim3(SEQL / 64, NBATCH * NHEAD), 256, 0, stream>>>(
            qkvh, qkvl, vth, vtl);

        attn_kernel<<<dim3(SEQL / 64, NBATCH * NHEAD), 256, 0, stream>>>(
            qkvh, qkvl, mask, P);

        pv_kernel<<<dim3(SEQL / 64, NBATCH * NHEAD), 256, 0, stream>>>(
            P, vth, vtl, atth, attl);

        // h += att @ Wo + bo   (K-split x2, atomic accumulate)
        mgemm_kernel<<<dim3(6, 32, 2), 256, 0, stream>>>(
            atth, attl, woh, wol, bo + l * DMODEL, h, nullptr, nullptr,
            DMODEL, DMODEL, 2);

        ln_kernel<<<ROWS, 256, 0, stream>>>(h, g2 + l * DMODEL, be2 + l * DMODEL, xnh, xnl);

        // ff = gelu(xn @ W1 + b1) -> f16 hi/lo directly
        mgemm_kernel<<<dim3(24, 32, 1), 256, 0, stream>>>(
            xnh, xnl, w1h, w1l, b1 + l * FFDIM, nullptr, ffh, ffl,
            FFDIM, DMODEL, 1 | 4);

        // h += ff @ W2 + b2    (K-split x4, atomic accumulate)
        mgemm_kernel<<<dim3(6, 32, 4), 256, 0, stream>>>(
            ffh, ffl, w2h, w2l, b2 + l * DMODEL, h, nullptr, nullptr,
            DMODEL, FFDIM, 2);
    }

    logits_kernel<<<NBATCH, 256, 0, stream>>>(h, Wc, bc, out);
}